// Round 8
// baseline (144.614 us; speedup 1.0000x reference)
//
#include <hip/hip_runtime.h>
#include <hip/hip_fp16.h>

// MaddnessMatmul round 8: fused single kernel, NO LDS A-tile.
//   out[m][n] = sum_c luts[c][enc(n,c)][m],  luts[c][k][m] = dot(B[m], P[c][k]).
//
// R5/R6/R7 post-mortem: three different pipeline structures all ~31us of
// kernels vs ~14us floor -> the shared piece is the LDS A-tile: 16.6KB/wave
// caps encode at 8 waves/CU and the dependent threshold chains (~120cyc LDS
// latency/level) can't hide at 2 waves/SIMD. R8 deletes the A-tile:
//  - each thread owns one row; gathers A[n*64+sd] straight from global. One
//    wave's gather = 64 distinct 64B lines = that wave's whole 16KB row-block
//    -> first gather populates L1, the other 63 hit L1/L2. No staging
//    instructions, no stage->encode fence, no convoy.
//  - LDS only 14.3KB/block (f16 LUT stride-24 + sv) -> 1024 blocks x 256 thr,
//    16 waves/CU (2x R7), 4 blocks/CU.
//  - thresholds by LDS index; sd via s_load_dwordx4 (wave-uniform).
//  - accumulate fused: even/odd packed-f16 sums, f32 combine (absmax ~1 <<
//    3.6 threshold); 16 coalesced dword store streams.
//  - lut_build: separate 1us kernel -> d_ws (f16 LUT).

#define NROWS 262144
#define DDIM  64
#define LSTR  24          // LDS halfs per LUT entry (48B, b128 banks <=2-way)
#define TPB   256
#define NBLK  1024        // 1024 * 256 = 262144 rows

typedef __attribute__((ext_vector_type(8))) _Float16 half8;
typedef __attribute__((ext_vector_type(4))) unsigned int u32x4;

__global__ __launch_bounds__(256) void lut_build(
    const float* __restrict__ B,      // [16][64]
    const float* __restrict__ P,      // [16][16][64]
    _Float16* __restrict__ lutw)      // [16][16][16] = c,k,m
{
    int o = blockIdx.x * 256 + threadIdx.x;   // o = c*256 + k*16 + m
    int m  = o & 15;
    int ck = o >> 4;
    const float4* Bp = (const float4*)(B + m * DDIM);
    const float4* Pp = (const float4*)(P + ck * DDIM);
    float dot = 0.f;
    #pragma unroll
    for (int q = 0; q < 16; ++q) {
        float4 b = Bp[q], p = Pp[q];
        dot += b.x * p.x + b.y * p.y + b.z * p.z + b.w * p.w;
    }
    lutw[o] = (_Float16)dot;
}

__global__ __launch_bounds__(TPB) void maddness_fused(
    const float* __restrict__ A,      // [N][64]
    const int*   __restrict__ sd,     // [16][4]
    const float* __restrict__ sv,     // [16][4][8]
    const _Float16* __restrict__ lutw,// [256][16] f16
    float* __restrict__ out)          // [16][N]
{
    __shared__ __align__(16) _Float16 lut_s[256 * LSTR];  // 12,288 B
    __shared__ float sv_s[512];                           //  2,048 B
    const int t = threadIdx.x;

    // stage f16 LUT (one 32B entry/thread, padded stride 24 halfs) + sv
    {
        const u32x4* src = (const u32x4*)(lutw + t * 16);
        u32x4 q0 = src[0], q1 = src[1];
        *(u32x4*)(lut_s + t * LSTR)     = q0;
        *(u32x4*)(lut_s + t * LSTR + 8) = q1;
        ((float2*)sv_s)[t] = ((const float2*)sv)[t];
    }
    __syncthreads();

    const int n = blockIdx.x * TPB + t;
    const float* __restrict__ Arow = A + (size_t)n * DDIM;
    const int4* __restrict__ sd4 = (const int4*)sd;

    half8 aE0 = {0,0,0,0,0,0,0,0}, aE1 = {0,0,0,0,0,0,0,0};
    half8 aO0 = {0,0,0,0,0,0,0,0}, aO1 = {0,0,0,0,0,0,0,0};

    #pragma unroll
    for (int c = 0; c < 16; ++c) {
        const int4 s4 = sd4[c];           // wave-uniform s_load_dwordx4
        // four gathers per codebook; first touch fills L1 with this wave's
        // 64-row block, the rest hit L1/L2. 16 independent c-chains.
        float x0 = Arow[s4.x];
        float x1 = Arow[s4.y];
        float x2 = Arow[s4.z];
        float x3 = Arow[s4.w];

        int g = (x0 > sv_s[c*32]) ? 1 : 0;
        g = (g << 1) | ((x1 > sv_s[c*32 +  8 + g]) ? 1 : 0);
        g = (g << 1) | ((x2 > sv_s[c*32 + 16 + g]) ? 1 : 0);
        g = (g << 1) | ((x3 > sv_s[c*32 + 24 + g]) ? 1 : 0);

        const _Float16* lp = lut_s + (c * 16 + g) * LSTR;
        half8 l0 = *(const half8*)(lp);
        half8 l1 = *(const half8*)(lp + 8);
        if (c & 1) { aO0 += l0; aO1 += l1; }
        else       { aE0 += l0; aE1 += l1; }
    }

    #pragma unroll
    for (int m = 0; m < 8; ++m) {
        out[(long)m       * NROWS + n] = (float)aE0[m] + (float)aO0[m];
        out[(long)(m + 8) * NROWS + n] = (float)aE1[m] + (float)aO1[m];
    }
}

extern "C" void kernel_launch(void* const* d_in, const int* in_sizes, int n_in,
                              void* d_out, int out_size, void* d_ws, size_t ws_size,
                              hipStream_t stream) {
    const float* A  = (const float*)d_in[0];
    const float* B  = (const float*)d_in[1];
    const float* P  = (const float*)d_in[2];
    const int*   sd = (const int*)d_in[3];
    const float* sv = (const float*)d_in[4];
    float* out = (float*)d_out;

    _Float16* lutw = (_Float16*)d_ws;   // 8 KB f16 LUT

    lut_build<<<dim3(16), dim3(256), 0, stream>>>(B, P, lutw);
    maddness_fused<<<dim3(NBLK), dim3(TPB), 0, stream>>>(A, sd, sv, lutw, out);
}

// Round 9
// 110.844 us; speedup vs baseline: 1.3047x; 1.3047x over previous
//
#include <hip/hip_runtime.h>
#include <hip/hip_fp16.h>

// MaddnessMatmul round 9: register-resident encode via ds_bpermute.
//   out[m][n] = sum_c luts[c][enc(n,c)][m],  luts[c][k][m] = dot(B[m], P[c][k]).
//
// R8 post-mortem: direct global gathers = 64 distinct lines/wave-instr ->
// ~1 line/cyc VMEM address pipe -> 27us serialization (FETCH was fine at
// 65MB; caches were never the problem). R5-R7: LDS A-tile caps occupancy at
// 8-10 waves/CU (256B/row) and serializes stage->fence->encode. R9 removes
// both: A stays in REGISTERS, cross-lane gather via ds_bpermute (full-rate
// LDS crossbar, no VMEM divergence, no A-LDS):
//  - wave pass = 4 rows: lane L loads float4 A[row0+(L>>4)][4*(L&15)..] (1KB
//    coalesced). Lane L encodes row0+(L>>4), codebook c=L&15: element at
//    source lane 16r+(sd>>2), component sd&3 -> 4 bpermute + 3 cndmask
//    (selector bits loop-invariant -> hoisted v_cmp masks).
//  - thresholds in 15 VGPRs/lane (lane owns codebook c): compare chain is
//    pure VALU, no LDS latency on the critical path.
//  - codes (4-bit g) round-trip a 20KB LDS buffer (stride-20 dwords,
//    wave-private region -> lgkmcnt fence only, no barrier/vmcnt drain).
//  - accum: int4 code read (16B-aligned), f16 LUT stride-24, even/odd packed
//    f16 sums, f32 combine (absmax ~1 << 3.6).
//  - LDS 12288+20480=32768 -> 5 blocks/CU; VGPR ~110 -> ~16 waves/CU.

#define NROWS 262144
#define LSTR  24          // halfs per LUT entry (48B)
#define CSTRD 20          // dwords per row in codes_s (80B, 16B-aligned)
#define TPB   256
#define NBLK  1024        // 1024 * 256 rows = 262144

typedef __attribute__((ext_vector_type(8))) _Float16 half8;
typedef __attribute__((ext_vector_type(4))) unsigned int u32x4;

#define WAVE_LDS_FENCE() asm volatile("s_waitcnt lgkmcnt(0)" ::: "memory")

__global__ __launch_bounds__(256) void lut_build(
    const float* __restrict__ B,      // [16][64]
    const float* __restrict__ P,      // [16][16][64]
    _Float16* __restrict__ lutw)      // [16][16][16] = c,k,m
{
    int o = blockIdx.x * 256 + threadIdx.x;   // o = c*256 + k*16 + m
    int m  = o & 15;
    int ck = o >> 4;
    const float4* Bp = (const float4*)(B + m * 64);
    const float4* Pp = (const float4*)(P + ck * 64);
    float dot = 0.f;
    #pragma unroll
    for (int q = 0; q < 16; ++q) {
        float4 b = Bp[q], p = Pp[q];
        dot += b.x * p.x + b.y * p.y + b.z * p.z + b.w * p.w;
    }
    lutw[o] = (_Float16)dot;
}

__global__ __launch_bounds__(TPB) void maddness_fused(
    const float* __restrict__ A,      // [N][64]
    const int*   __restrict__ sd,     // [16][4]
    const float* __restrict__ sv,     // [16][4][8]
    const _Float16* __restrict__ lutw,// [256][16] f16
    float* __restrict__ out)          // [16][N]
{
    __shared__ __align__(16) _Float16 lut_s[256 * LSTR];  // 12,288 B
    __shared__ __align__(16) int codes_s[256 * CSTRD];    // 20,480 B

    const int t    = threadIdx.x;
    const int lane = t & 63;
    const int w    = t >> 6;
    const int r    = lane >> 4;    // row-within-quad this lane loads/encodes
    const int c    = lane & 15;    // codebook this lane owns

    // ---- stage f16 LUT (one 32B entry/thread, stride 24 halfs) ----
    {
        const u32x4* src = (const u32x4*)(lutw + t * 16);
        u32x4 q0 = src[0], q1 = src[1];
        *(u32x4*)(lut_s + t * LSTR)     = q0;
        *(u32x4*)(lut_s + t * LSTR + 8) = q1;
    }

    // ---- per-lane constants: split dims (bpermute addrs) + thresholds ----
    const int sd0 = sd[c*4+0], sd1 = sd[c*4+1], sd2 = sd[c*4+2], sd3 = sd[c*4+3];
    const int ba0 = r*64 + (sd0 & 60);   // bpermute byte addr = 4*srclane
    const int ba1 = r*64 + (sd1 & 60);
    const int ba2 = r*64 + (sd2 & 60);
    const int ba3 = r*64 + (sd3 & 60);

    const float* svc = sv + c * 32;
    const float v0   = svc[0];
    const float v1a  = svc[8],  v1b = svc[9];
    const float v2_0 = svc[16], v2_1 = svc[17], v2_2 = svc[18], v2_3 = svc[19];
    const float v3_0 = svc[24], v3_1 = svc[25], v3_2 = svc[26], v3_3 = svc[27];
    const float v3_4 = svc[28], v3_5 = svc[29], v3_6 = svc[30], v3_7 = svc[31];

    __syncthreads();   // LUT staged (once; also drains the init loads)

    const int rowbase = blockIdx.x * TPB + w * 64;
    const float4* A4 = (const float4*)A;

    // cross-lane gather of column sd from the 4-row register block:
    // 4 bpermute (one per float4 component) + select by sd&3 (hoisted masks)
#define GATHER(xdst, ba, sdl, Av)                                          \
    {                                                                      \
        int y0 = __builtin_amdgcn_ds_bpermute((ba), __float_as_int((Av).x));\
        int y1 = __builtin_amdgcn_ds_bpermute((ba), __float_as_int((Av).y));\
        int y2 = __builtin_amdgcn_ds_bpermute((ba), __float_as_int((Av).z));\
        int y3 = __builtin_amdgcn_ds_bpermute((ba), __float_as_int((Av).w));\
        int s01 = ((sdl) & 1) ? y1 : y0;                                   \
        int s23 = ((sdl) & 1) ? y3 : y2;                                   \
        xdst = __int_as_float(((sdl) & 2) ? s23 : s01);                    \
    }

    #pragma unroll
    for (int p = 0; p < 16; ++p) {
        // 4 rows, coalesced 1KB: lane L -> row rowbase+4p+(L>>4), cols 4(L&15)
        const float4 Av = A4[(size_t)(rowbase + 4*p) * 16 + lane];

        float x0, x1, x2, x3;
        GATHER(x0, ba0, sd0, Av);
        GATHER(x1, ba1, sd1, Av);
        GATHER(x2, ba2, sd2, Av);
        GATHER(x3, ba3, sd3, Av);

        // threshold tree: registers only (no LDS on the critical path)
        int g = (x0 > v0) ? 1 : 0;
        float t1 = g ? v1b : v1a;
        g = (g << 1) | ((x1 > t1) ? 1 : 0);
        float ta = (g & 1) ? v2_1 : v2_0;
        float tb = (g & 1) ? v2_3 : v2_2;
        float t2 = (g & 2) ? tb : ta;
        g = (g << 1) | ((x2 > t2) ? 1 : 0);
        float u0 = (g & 1) ? v3_1 : v3_0;
        float u1 = (g & 1) ? v3_3 : v3_2;
        float u2 = (g & 1) ? v3_5 : v3_4;
        float u3 = (g & 1) ? v3_7 : v3_6;
        float w0 = (g & 2) ? u1 : u0;
        float w1 = (g & 2) ? u3 : u2;
        float t3 = (g & 4) ? w1 : w0;
        g = (g << 1) | ((x3 > t3) ? 1 : 0);

        // wave-private codes region: row (w*64 + 4p + r), slot c
        codes_s[(w*64 + 4*p + r) * CSTRD + c] = g;
    }
#undef GATHER

    WAVE_LDS_FENCE();   // own-wave ds_write -> ds_read ordering; no vmcnt drain

    // ---- accumulate: lane owns row w*64+lane = t ----
    const int* crow = codes_s + (size_t)t * CSTRD;
    const int4 q0 = *(const int4*)(crow);
    const int4 q1 = *(const int4*)(crow + 4);
    const int4 q2 = *(const int4*)(crow + 8);
    const int4 q3 = *(const int4*)(crow + 12);

    half8 aE0 = {0,0,0,0,0,0,0,0}, aE1 = {0,0,0,0,0,0,0,0};
    half8 aO0 = {0,0,0,0,0,0,0,0}, aO1 = {0,0,0,0,0,0,0,0};

#define ACC(cc, gg)                                                        \
    {                                                                      \
        const _Float16* lp = lut_s + ((cc) * 16 + (gg)) * LSTR;            \
        half8 l0 = *(const half8*)(lp);                                    \
        half8 l1 = *(const half8*)(lp + 8);                                \
        if ((cc) & 1) { aO0 += l0; aO1 += l1; }                            \
        else          { aE0 += l0; aE1 += l1; }                            \
    }
    ACC(0,  q0.x) ACC(1,  q0.y) ACC(2,  q0.z) ACC(3,  q0.w)
    ACC(4,  q1.x) ACC(5,  q1.y) ACC(6,  q1.z) ACC(7,  q1.w)
    ACC(8,  q2.x) ACC(9,  q2.y) ACC(10, q2.z) ACC(11, q2.w)
    ACC(12, q3.x) ACC(13, q3.y) ACC(14, q3.z) ACC(15, q3.w)
#undef ACC

    const int n = blockIdx.x * TPB + t;
    #pragma unroll
    for (int m = 0; m < 8; ++m) {
        out[(long)m       * NROWS + n] = (float)aE0[m] + (float)aO0[m];
        out[(long)(m + 8) * NROWS + n] = (float)aE1[m] + (float)aO1[m];
    }
}

extern "C" void kernel_launch(void* const* d_in, const int* in_sizes, int n_in,
                              void* d_out, int out_size, void* d_ws, size_t ws_size,
                              hipStream_t stream) {
    const float* A  = (const float*)d_in[0];
    const float* B  = (const float*)d_in[1];
    const float* P  = (const float*)d_in[2];
    const int*   sd = (const int*)d_in[3];
    const float* sv = (const float*)d_in[4];
    float* out = (float*)d_out;

    _Float16* lutw = (_Float16*)d_ws;   // 8 KB f16 LUT

    lut_build<<<dim3(16), dim3(256), 0, stream>>>(B, P, lutw);
    maddness_fused<<<dim3(NBLK), dim3(TPB), 0, stream>>>(A, sd, sv, lutw, out);
}